// Round 7
// baseline (7708.067 us; speedup 1.0000x reference)
//
#include <hip/hip_runtime.h>

typedef unsigned short u16;
typedef unsigned int u32;
typedef short bf16x8 __attribute__((ext_vector_type(8)));
typedef float f32x4 __attribute__((ext_vector_type(4)));

#define S_LEN 500
#define NB 256
#define EDIM 128

__device__ __forceinline__ float bf2f(u16 u) { return __uint_as_float(((u32)u) << 16); }
__device__ __forceinline__ u16 f2bf(float f) {
    u32 x = __float_as_uint(f);
    x += 0x7FFFu + ((x >> 16) & 1u);   // round-to-nearest-even
    return (u16)(x >> 16);
}
__device__ __forceinline__ float fexp(float x) { return __builtin_amdgcn_exp2f(x * 1.44269504089f); }
__device__ __forceinline__ float frcp(float x) { return __builtin_amdgcn_rcpf(x); }
__device__ __forceinline__ float sigm(float x) { return frcp(1.0f + fexp(-x)); }
__device__ __forceinline__ float tanh_(float x) { return 1.0f - 2.0f * frcp(1.0f + fexp(2.0f * x)); }
__device__ __forceinline__ int iclamp(int v, int hi) { return v < 0 ? 0 : (v > hi ? hi : v); }

// ---------------------------------------------------------------------------
// Runtime float-dtype detection from q_embedding bit patterns (wave-uniform).
// ---------------------------------------------------------------------------
__device__ __forceinline__ bool detect_bf16(const void* q) {
    const u16* w = (const u16*)q;
    int plaus = 0;
#pragma unroll 1
    for (int i = 0; i < 64; ++i) {
        const u16 v = w[2 * i];
        const int e = (v >> 7) & 0xFF;
        plaus += (v == 0 || (e >= 100 && e <= 130)) ? 1 : 0;
    }
    return plaus >= 48;
}
__device__ __forceinline__ float ldF(const void* p, int i, bool bf) {
    return bf ? bf2f(((const u16*)p)[i]) : ((const float*)p)[i];
}
template <bool BF>
__device__ __forceinline__ bf16x8 ldfragT(const void* p, int i) {
    if (BF) return *(const bf16x8*)((const u16*)p + i);
    const float* f = (const float*)p + i;
    bf16x8 r;
#pragma unroll
    for (int e = 0; e < 8; ++e) r[e] = (short)f2bf(f[e]);
    return r;
}

__global__ void dimkt_sentinel(u16* __restrict__ out, u16 val) {
    out[blockIdx.x * 256 + threadIdx.x] = val;
}

// ---------------------------------------------------------------------------
// K0: tiny gather-table precompute (always-fp32 outputs, packed for the scan).
// ---------------------------------------------------------------------------
__global__ void dimkt_tabs(const void* __restrict__ q_emb,
                           const void* __restrict__ c_tab, const void* __restrict__ sd_tab,
                           const void* __restrict__ qd_tab, const void* __restrict__ a_tab,
                           const void* __restrict__ W1, const void* __restrict__ W4,
                           const void* __restrict__ W5, const void* __restrict__ W6,
                           const void* __restrict__ b4, const void* __restrict__ b5,
                           const void* __restrict__ b6,
                           float* __restrict__ cW1p, float* __restrict__ sdQ,
                           float* __restrict__ qdQ, float* __restrict__ aW6p,
                           float* __restrict__ c4t, float* __restrict__ c5t) {
    const bool bf = detect_bf16(q_emb);
    __shared__ float src[128];
    const int r = blockIdx.x, n = threadIdx.x;
    const int w = n >> 5, jj = (n >> 4) & 1, l = n & 15;
    const void* srcp; const void* W; const void* bias = nullptr;
    int soff, koff, ld, oidx; float* outp; bool mask;
    if (r < 1001)      { srcp = c_tab;  soff = r * 128;               W = W1; koff = 128; ld = 512; outp = cW1p; oidx = r * 128 + w * 32 + l * 2 + jj;        mask = (r == 0); }
    else if (r < 1103) { int rr = r - 1001; srcp = sd_tab; soff = rr * 128; W = W1; koff = 256; ld = 512; outp = sdQ;  oidx = rr * 256 + w * 64 + l * 4 + jj;     mask = (rr == 0); }
    else if (r < 1205) { int rr = r - 1103; srcp = qd_tab; soff = rr * 128; W = W1; koff = 384; ld = 512; outp = qdQ;  oidx = rr * 256 + w * 64 + l * 4 + jj;     mask = (rr == 0); }
    else if (r < 1307) { int rr = r - 1205; srcp = sd_tab; soff = rr * 128; W = W6; koff = 256; ld = 512; outp = sdQ;  oidx = rr * 256 + w * 64 + l * 4 + 2 + jj; mask = (rr == 0); }
    else if (r < 1409) { int rr = r - 1307; srcp = qd_tab; soff = rr * 128; W = W6; koff = 384; ld = 512; outp = qdQ;  oidx = rr * 256 + w * 64 + l * 4 + 2 + jj; mask = (rr == 0); }
    else if (r < 1411) { int rr = r - 1409; srcp = a_tab;  soff = rr * 128; W = W6; koff = 128; ld = 512; outp = aW6p; oidx = rr * 128 + w * 32 + l * 2 + jj;     bias = b6; mask = false; }
    else if (r < 1413) { int rr = r - 1411; srcp = a_tab;  soff = rr * 128; W = W4; koff = 128; ld = 256; outp = c4t;  oidx = rr * 128 + n;                       bias = b4; mask = false; }
    else               { int rr = r - 1413; srcp = a_tab;  soff = rr * 128; W = W5; koff = 128; ld = 256; outp = c5t;  oidx = rr * 128 + n;                       bias = b5; mask = false; }
    src[n] = ldF(srcp, soff + n, bf);
    __syncthreads();
    float acc = 0.f;
    if (!mask) {
        for (int k = 0; k < 128; ++k) acc += src[k] * ldF(W, n * ld + koff + k, bf);
        if (bias) acc += ldF(bias, n, bf);
    }
    outp[oidx] = acc;
}

// ---------------------------------------------------------------------------
// K2: fused 500-step scan. 8 WGs x 512 threads; each WG owns two 16-row
// M-tiles (mt = tid>>8) -> 2 co-resident waves per SIMD (TLP).
// Register budget via LLVM attrs: flat_work_group_size(512,512) +
// waves_per_eu(2,2) -> VGPR cap 512-pool/2 = 256 >= ~216 needed -> NO spill.
// (R5/R6 evidence: __launch_bounds__(512[,2]) caps at 128 and spills 6 MB.)
// ---------------------------------------------------------------------------
template <bool BF>
__global__ __attribute__((amdgpu_flat_work_group_size(512, 512), amdgpu_waves_per_eu(2, 2)))
void dimkt_scan(
    const void* __restrict__ q_emb,
    const int* __restrict__ cI, const int* __restrict__ sI,
    const int* __restrict__ qI, const int* __restrict__ aI,
    const void* __restrict__ W1, const void* __restrict__ b1,
    const void* __restrict__ W2, const void* __restrict__ b2,
    const void* __restrict__ W3, const void* __restrict__ b3,
    const void* __restrict__ W4, const void* __restrict__ W5,
    const void* __restrict__ W6, const void* __restrict__ knowledge,
    const float* __restrict__ cW1p, const float* __restrict__ sdQ,
    const float* __restrict__ qdQ, const float* __restrict__ aW6p,
    const float* __restrict__ c4t, const float* __restrict__ c5t,
    void* __restrict__ outv) {
    if (detect_bf16(q_emb) != BF) return;   // wrong specialization: uniform exit
    // 136-ushort row stride: 272B = 17*16B -> 16B-aligned ds_read_b128
    __shared__ __align__(16) u16 kbuf[2][16][136];
    __shared__ __align__(16) u16 qqbuf[2][16][136];
    __shared__ __align__(16) u16 sdbuf[2][16][136];

    const int tid = threadIdx.x;
    const int mt = tid >> 8;               // M-tile 0/1
    const int wv = (tid >> 6) & 3;         // column-wave within M-tile
    const int lane = tid & 63;
    const int quad = lane >> 4, l15 = lane & 15;
    const int b0 = blockIdx.x * 32 + mt * 16;

    // ---- stationary weight fragments (registers, 500-step resident) ----
    bf16x8 fW1[2][4], fW2[2][4], fW3[2][4], fW4[2][4], fW5[2][4], fW6[2][4];
    float b1v[2], b2v[2], b3v[2], c4_0[2], c4_1[2], c5_0[2], c5_1[2];
    int col_[2];
#pragma unroll
    for (int j = 0; j < 2; ++j) {
        const int col = wv * 32 + j * 16 + l15;
        col_[j] = col;
#pragma unroll
        for (int ks = 0; ks < 4; ++ks) {
            const int ko = ks * 32 + quad * 8;
            fW1[j][ks] = ldfragT<BF>(W1, col * 512 + ko);   // W1[:, :128]
            fW2[j][ks] = ldfragT<BF>(W2, col * 128 + ko);
            fW3[j][ks] = ldfragT<BF>(W3, col * 128 + ko);
            fW4[j][ks] = ldfragT<BF>(W4, col * 256 + ko);   // W4[:, :128]
            fW5[j][ks] = ldfragT<BF>(W5, col * 256 + ko);   // W5[:, :128]
            fW6[j][ks] = ldfragT<BF>(W6, col * 512 + ko);   // W6[:, :128]
        }
        b1v[j] = ldF(b1, col, BF);
        b2v[j] = ldF(b2, col, BF);
        b3v[j] = ldF(b3, col, BF);
        c4_0[j] = c4t[col]; c4_1[j] = c4t[128 + col];
        c5_0[j] = c5t[col]; c5_1[j] = c5t[128 + col];
    }

    // ---- t=0 init: gathers, inp_0 via MFMA, kbuf/qqbuf, z6c ----
    float kold[2][4], z6c[2][4], g[2][4];
    int ac[4];
    {
        float inpAdd0[2][4];
#pragma unroll
        for (int i = 0; i < 4; ++i) {
            const int off = (b0 + quad * 4 + i) * S_LEN + 0;
            const int cx = iclamp(cI[off], 1000);
            const int sx = iclamp(sI[off], 101);
            const int qx = iclamp(qI[off], 101);
            const int ax = iclamp(aI[off], 1);
            ac[i] = ax;
            const float2 cg = *(const float2*)(cW1p + cx * 128 + wv * 32 + l15 * 2);
            const float4 sg = *(const float4*)(sdQ + sx * 256 + wv * 64 + l15 * 4);
            const float4 qg = *(const float4*)(qdQ + qx * 256 + wv * 64 + l15 * 4);
            const float2 ag = *(const float2*)(aW6p + ax * 128 + wv * 32 + l15 * 2);
            inpAdd0[0][i] = cg.x + sg.x + qg.x + b1v[0];
            inpAdd0[1][i] = cg.y + sg.y + qg.y + b1v[1];
            z6c[0][i] = ag.x + sg.z + qg.z;
            z6c[1][i] = ag.y + sg.w + qg.w;
        }
        bf16x8 ae0[4];
#pragma unroll
        for (int ks = 0; ks < 4; ++ks)
            ae0[ks] = ldfragT<BF>(q_emb, ((b0 + l15) * S_LEN + 0) * EDIM + ks * 32 + quad * 8);
        f32x4 Y1[2];
#pragma unroll
        for (int j = 0; j < 2; ++j) {
            Y1[j] = (f32x4){inpAdd0[j][0], inpAdd0[j][1], inpAdd0[j][2], inpAdd0[j][3]};
#pragma unroll
            for (int ks = 0; ks < 4; ++ks)
                Y1[j] = __builtin_amdgcn_mfma_f32_16x16x32_bf16(ae0[ks], fW1[j][ks], Y1[j], 0, 0, 0);
        }
#pragma unroll
        for (int j = 0; j < 2; ++j) {
            const float k0 = ldF(knowledge, col_[j], BF);
#pragma unroll
            for (int i = 0; i < 4; ++i) {
                kold[j][i] = k0;
                const int row = quad * 4 + i;
                kbuf[mt][row][col_[j]] = f2bf(k0);
                qqbuf[mt][row][col_[j]] = f2bf(k0 - Y1[j][i]);
            }
        }
    }
    // ---- prime pipeline: q_emb[1] fragments + raw idx[1] ----
    bf16x8 aeNow[4], aeFut[4];
#pragma unroll
    for (int ks = 0; ks < 4; ++ks)
        aeNow[ks] = ldfragT<BF>(q_emb, ((b0 + l15) * S_LEN + 1) * EDIM + ks * 32 + quad * 8);
    int cN[4], sN[4], qN[4], aN[4], cF[4], sF[4], qF[4], aF[4];
#pragma unroll
    for (int i = 0; i < 4; ++i) {
        const int off = (b0 + quad * 4 + i) * S_LEN + 1;
        cN[i] = cI[off]; sN[i] = sI[off]; qN[i] = qI[off]; aN[i] = aI[off];
    }
    __syncthreads();

#pragma unroll 1
    for (int t = 0; t < S_LEN; ++t) {
        // ---- issue prefetch: q_emb/idx for t+2 (raw, consumed next iter) ----
        const int tf = (t + 2 < S_LEN) ? t + 2 : S_LEN - 1;
#pragma unroll
        for (int ks = 0; ks < 4; ++ks)
            aeFut[ks] = ldfragT<BF>(q_emb, ((b0 + l15) * S_LEN + tf) * EDIM + ks * 32 + quad * 8);
#pragma unroll
        for (int i = 0; i < 4; ++i) {
            const int off = (b0 + quad * 4 + i) * S_LEN + tf;
            cF[i] = cI[off]; sF[i] = sI[off]; qF[i] = qI[off]; aF[i] = aI[off];
        }
        // ---- gathers for t+1 (clamp raw idx loaded last iter; consumed late in C)
        float2 cg[4], ag[4];
        float4 sg[4], qg[4];
        int an[4];
#pragma unroll
        for (int i = 0; i < 4; ++i) {
            const int cx = iclamp(cN[i], 1000), sx = iclamp(sN[i], 101);
            const int qx = iclamp(qN[i], 101),  ax = iclamp(aN[i], 1);
            an[i] = ax;
            cg[i] = *(const float2*)(cW1p + cx * 128 + wv * 32 + l15 * 2);
            sg[i] = *(const float4*)(sdQ + sx * 256 + wv * 64 + l15 * 4);
            qg[i] = *(const float4*)(qdQ + qx * 256 + wv * 64 + l15 * 4);
            ag[i] = *(const float2*)(aW6p + ax * 128 + wv * 32 + l15 * 2);
        }

        // ---- phase B: Y2/Y3 on qq, Y6 on k, Y1n on ae(t+1); sdft -> LDS ----
        bf16x8 aq[4], ak[4];
#pragma unroll
        for (int ks = 0; ks < 4; ++ks) {
            aq[ks] = *(const bf16x8*)&qqbuf[mt][l15][ks * 32 + quad * 8];
            ak[ks] = *(const bf16x8*)&kbuf[mt][l15][ks * 32 + quad * 8];
        }
        f32x4 Y2[2], Y3[2], Y6[2], Y1n[2];
#pragma unroll
        for (int j = 0; j < 2; ++j) {
            Y2[j] = (f32x4){b2v[j], b2v[j], b2v[j], b2v[j]};
            Y3[j] = (f32x4){b3v[j], b3v[j], b3v[j], b3v[j]};
            Y6[j] = (f32x4){z6c[j][0], z6c[j][1], z6c[j][2], z6c[j][3]};
            Y1n[j] = (f32x4){b1v[j], b1v[j], b1v[j], b1v[j]};
#pragma unroll
            for (int ks = 0; ks < 4; ++ks) {
                Y2[j] = __builtin_amdgcn_mfma_f32_16x16x32_bf16(aq[ks], fW2[j][ks], Y2[j], 0, 0, 0);
                Y3[j] = __builtin_amdgcn_mfma_f32_16x16x32_bf16(aq[ks], fW3[j][ks], Y3[j], 0, 0, 0);
                Y6[j] = __builtin_amdgcn_mfma_f32_16x16x32_bf16(ak[ks], fW6[j][ks], Y6[j], 0, 0, 0);
                Y1n[j] = __builtin_amdgcn_mfma_f32_16x16x32_bf16(aeNow[ks], fW1[j][ks], Y1n[j], 0, 0, 0);
            }
        }
#pragma unroll
        for (int j = 0; j < 2; ++j)
#pragma unroll
            for (int i = 0; i < 4; ++i) {
                const float sdv = sigm(Y2[j][i]) * tanh_(Y3[j][i]);
                sdbuf[mt][quad * 4 + i][col_[j]] = f2bf(sdv);
                g[j][i] = sigm(Y6[j][i]);
            }
        __syncthreads();

        // ---- phase C: Y4/Y5 on sdft; k update; write k/qq for t+1 ----
        bf16x8 as[4];
#pragma unroll
        for (int ks = 0; ks < 4; ++ks)
            as[ks] = *(const bf16x8*)&sdbuf[mt][l15][ks * 32 + quad * 8];
        f32x4 Y4[2], Y5[2];
#pragma unroll
        for (int j = 0; j < 2; ++j) {
            Y4[j] = (f32x4){ac[0] ? c4_1[j] : c4_0[j], ac[1] ? c4_1[j] : c4_0[j],
                            ac[2] ? c4_1[j] : c4_0[j], ac[3] ? c4_1[j] : c4_0[j]};
            Y5[j] = (f32x4){ac[0] ? c5_1[j] : c5_0[j], ac[1] ? c5_1[j] : c5_0[j],
                            ac[2] ? c5_1[j] : c5_0[j], ac[3] ? c5_1[j] : c5_0[j]};
#pragma unroll
            for (int ks = 0; ks < 4; ++ks) {
                Y4[j] = __builtin_amdgcn_mfma_f32_16x16x32_bf16(as[ks], fW4[j][ks], Y4[j], 0, 0, 0);
                Y5[j] = __builtin_amdgcn_mfma_f32_16x16x32_bf16(as[ks], fW5[j][ks], Y5[j], 0, 0, 0);
            }
        }
#pragma unroll
        for (int j = 0; j < 2; ++j)
#pragma unroll
            for (int i = 0; i < 4; ++i) {
                const float pk = sigm(Y4[j][i]) * tanh_(Y5[j][i]);
                const float kn = g[j][i] * kold[j][i] + (1.0f - g[j][i]) * pk;
                kold[j][i] = kn;
                const float inpn = Y1n[j][i] +
                    ((j == 0) ? (cg[i].x + sg[i].x + qg[i].x) : (cg[i].y + sg[i].y + qg[i].y));
                const int row = quad * 4 + i;
                kbuf[mt][row][col_[j]] = f2bf(kn);
                qqbuf[mt][row][col_[j]] = f2bf(kn - inpn);   // qq_{t+1}
            }
        // ---- rotate pipeline registers; z6 for t+1 ----
#pragma unroll
        for (int i = 0; i < 4; ++i) {
            z6c[0][i] = ag[i].x + sg[i].z + qg[i].z;
            z6c[1][i] = ag[i].y + sg[i].w + qg[i].w;
            ac[i] = an[i];
            cN[i] = cF[i]; sN[i] = sF[i]; qN[i] = qF[i]; aN[i] = aF[i];
        }
#pragma unroll
        for (int ks = 0; ks < 4; ++ks) aeNow[ks] = aeFut[ks];
        __syncthreads();
    }

    // ---- epilogue: out = sigmoid(k_final), [B][E], dtype matches input ----
#pragma unroll
    for (int j = 0; j < 2; ++j)
#pragma unroll
        for (int i = 0; i < 4; ++i) {
            const int row = quad * 4 + i;
            const float v = sigm(kold[j][i]);
            const int off = (b0 + row) * EDIM + col_[j];
            if (BF) ((u16*)outv)[off] = f2bf(v);
            else    ((float*)outv)[off] = v;
        }
}

// ---------------------------------------------------------------------------
extern "C" void kernel_launch(void* const* d_in, const int* in_sizes, int n_in,
                              void* d_out, int out_size, void* d_ws, size_t ws_size,
                              hipStream_t stream) {
    static const int exp_sizes[27] = {
        128000, 128000, 128000, 128000, 128000,
        128000, 128000, 128000, 128000,
        16384000,
        128128, 13056, 13056, 256, 128,
        65536, 128, 16384, 128, 16384, 128,
        32768, 128, 32768, 128, 65536, 128
    };
    bool sizes_ok = (n_in == 27) && (out_size == 32768);
    if (sizes_ok)
        for (int i = 0; i < 27; ++i)
            if (in_sizes[i] != exp_sizes[i]) { sizes_ok = false; break; }
    if (!sizes_ok) {
        dimkt_sentinel<<<dim3(128), dim3(256), 0, stream>>>((u16*)d_out, (u16)0xC080); // -4.0
        return;
    }
    const size_t WS_NEED = 724480;
    if (ws_size < WS_NEED) {
        dimkt_sentinel<<<dim3(128), dim3(256), 0, stream>>>((u16*)d_out, (u16)0x4110); // 9.0
        return;
    }

    const int* c   = (const int*)d_in[1];
    const int* sd  = (const int*)d_in[2];
    const int* qd  = (const int*)d_in[3];
    const int* a   = (const int*)d_in[4];
    const void* q_emb = d_in[9];
    const void* c_tab = d_in[10];
    const void* sd_tab = d_in[11];
    const void* qd_tab = d_in[12];
    const void* a_tab = d_in[13];
    const void* knowledge = d_in[14];
    const void* W1 = d_in[15]; const void* b1 = d_in[16];
    const void* W2 = d_in[17]; const void* b2 = d_in[18];
    const void* W3 = d_in[19]; const void* b3 = d_in[20];
    const void* W4 = d_in[21]; const void* b4 = d_in[22];
    const void* W5 = d_in[23]; const void* b5 = d_in[24];
    const void* W6 = d_in[25]; const void* b6 = d_in[26];

    float* wsf = (float*)d_ws;
    float* cW1p = wsf;                 // 1001*128
    float* sdQ  = wsf + 128128;        // 102*256
    float* qdQ  = wsf + 154240;        // 102*256
    float* aW6p = wsf + 180352;        // 2*128 (+b6)
    float* c4t  = wsf + 180608;        // 2*128 (+b4)
    float* c5t  = wsf + 180864;        // 2*128 (+b5), ends at 181120 floats

    dimkt_tabs<<<dim3(1415), dim3(128), 0, stream>>>(
        q_emb, c_tab, sd_tab, qd_tab, a_tab, W1, W4, W5, W6, b4, b5, b6,
        cW1p, sdQ, qdQ, aW6p, c4t, c5t);

    dimkt_scan<true><<<dim3(8), dim3(512), 0, stream>>>(
        q_emb, c, sd, qd, a, W1, b1, W2, b2, W3, b3, W4, W5, W6, knowledge,
        cW1p, sdQ, qdQ, aW6p, c4t, c5t, d_out);
    dimkt_scan<false><<<dim3(8), dim3(512), 0, stream>>>(
        q_emb, c, sd, qd, a, W1, b1, W2, b2, W3, b3, W4, W5, W6, knowledge,
        cW1p, sdQ, qdQ, aW6p, c4t, c5t, d_out);
}

// Round 8
// 1946.328 us; speedup vs baseline: 3.9603x; 3.9603x over previous
//
#include <hip/hip_runtime.h>

typedef unsigned short u16;
typedef unsigned int u32;
typedef short bf16x8 __attribute__((ext_vector_type(8)));
typedef float f32x4 __attribute__((ext_vector_type(4)));

#define S_LEN 500
#define NB 256
#define EDIM 128

__device__ __forceinline__ float bf2f(u16 u) { return __uint_as_float(((u32)u) << 16); }
__device__ __forceinline__ u16 f2bf(float f) {
    u32 x = __float_as_uint(f);
    x += 0x7FFFu + ((x >> 16) & 1u);   // round-to-nearest-even
    return (u16)(x >> 16);
}
__device__ __forceinline__ float fexp(float x) { return __builtin_amdgcn_exp2f(x * 1.44269504089f); }
__device__ __forceinline__ float frcp(float x) { return __builtin_amdgcn_rcpf(x); }
__device__ __forceinline__ float sigm(float x) { return frcp(1.0f + fexp(-x)); }
__device__ __forceinline__ float tanh_(float x) { return 1.0f - 2.0f * frcp(1.0f + fexp(2.0f * x)); }
__device__ __forceinline__ int iclamp(int v, int hi) { return v < 0 ? 0 : (v > hi ? hi : v); }

// ---------------------------------------------------------------------------
// Workgroup sync WITHOUT s_barrier: lane-0 atomicAdd on an LDS counter +
// broadcast ds_read poll. No s_barrier => compiler emits NO vmcnt(0) drain,
// so in-flight global prefetch survives across phase boundaries.
// ---------------------------------------------------------------------------
__device__ __forceinline__ void wgsync(volatile int* c, int target) {
    __asm__ volatile("s_waitcnt lgkmcnt(0)" ::: "memory");  // prior LDS writes done
    if ((threadIdx.x & 63) == 0) atomicAdd((int*)c, 1);
    while (*c < target) {}
    __asm__ volatile("" ::: "memory");
}

// ---------------------------------------------------------------------------
// Runtime float-dtype detection from q_embedding bit patterns (wave-uniform).
// ---------------------------------------------------------------------------
__device__ __forceinline__ bool detect_bf16(const void* q) {
    const u16* w = (const u16*)q;
    int plaus = 0;
#pragma unroll 1
    for (int i = 0; i < 64; ++i) {
        const u16 v = w[2 * i];
        const int e = (v >> 7) & 0xFF;
        plaus += (v == 0 || (e >= 100 && e <= 130)) ? 1 : 0;
    }
    return plaus >= 48;
}
__device__ __forceinline__ float ldF(const void* p, int i, bool bf) {
    return bf ? bf2f(((const u16*)p)[i]) : ((const float*)p)[i];
}
template <bool BF>
__device__ __forceinline__ bf16x8 ldfragT(const void* p, int i) {
    if (BF) return *(const bf16x8*)((const u16*)p + i);
    const float* f = (const float*)p + i;
    bf16x8 r;
#pragma unroll
    for (int e = 0; e < 8; ++e) r[e] = (short)f2bf(f[e]);
    return r;
}

__global__ void dimkt_sentinel(u16* __restrict__ out, u16 val) {
    out[blockIdx.x * 256 + threadIdx.x] = val;
}

// ---------------------------------------------------------------------------
// K0: tiny gather-table precompute (always-fp32 outputs, packed for the scan).
// ---------------------------------------------------------------------------
__global__ void dimkt_tabs(const void* __restrict__ q_emb,
                           const void* __restrict__ c_tab, const void* __restrict__ sd_tab,
                           const void* __restrict__ qd_tab, const void* __restrict__ a_tab,
                           const void* __restrict__ W1, const void* __restrict__ W4,
                           const void* __restrict__ W5, const void* __restrict__ W6,
                           const void* __restrict__ b4, const void* __restrict__ b5,
                           const void* __restrict__ b6,
                           float* __restrict__ cW1p, float* __restrict__ sdQ,
                           float* __restrict__ qdQ, float* __restrict__ aW6p,
                           float* __restrict__ c4t, float* __restrict__ c5t) {
    const bool bf = detect_bf16(q_emb);
    __shared__ float src[128];
    const int r = blockIdx.x, n = threadIdx.x;
    const int w = n >> 5, jj = (n >> 4) & 1, l = n & 15;
    const void* srcp; const void* W; const void* bias = nullptr;
    int soff, koff, ld, oidx; float* outp; bool mask;
    if (r < 1001)      { srcp = c_tab;  soff = r * 128;               W = W1; koff = 128; ld = 512; outp = cW1p; oidx = r * 128 + w * 32 + l * 2 + jj;        mask = (r == 0); }
    else if (r < 1103) { int rr = r - 1001; srcp = sd_tab; soff = rr * 128; W = W1; koff = 256; ld = 512; outp = sdQ;  oidx = rr * 256 + w * 64 + l * 4 + jj;     mask = (rr == 0); }
    else if (r < 1205) { int rr = r - 1103; srcp = qd_tab; soff = rr * 128; W = W1; koff = 384; ld = 512; outp = qdQ;  oidx = rr * 256 + w * 64 + l * 4 + jj;     mask = (rr == 0); }
    else if (r < 1307) { int rr = r - 1205; srcp = sd_tab; soff = rr * 128; W = W6; koff = 256; ld = 512; outp = sdQ;  oidx = rr * 256 + w * 64 + l * 4 + 2 + jj; mask = (rr == 0); }
    else if (r < 1409) { int rr = r - 1307; srcp = qd_tab; soff = rr * 128; W = W6; koff = 384; ld = 512; outp = qdQ;  oidx = rr * 256 + w * 64 + l * 4 + 2 + jj; mask = (rr == 0); }
    else if (r < 1411) { int rr = r - 1409; srcp = a_tab;  soff = rr * 128; W = W6; koff = 128; ld = 512; outp = aW6p; oidx = rr * 128 + w * 32 + l * 2 + jj;     bias = b6; mask = false; }
    else if (r < 1413) { int rr = r - 1411; srcp = a_tab;  soff = rr * 128; W = W4; koff = 128; ld = 256; outp = c4t;  oidx = rr * 128 + n;                       bias = b4; mask = false; }
    else               { int rr = r - 1413; srcp = a_tab;  soff = rr * 128; W = W5; koff = 128; ld = 256; outp = c5t;  oidx = rr * 128 + n;                       bias = b5; mask = false; }
    src[n] = ldF(srcp, soff + n, bf);
    __syncthreads();
    float acc = 0.f;
    if (!mask) {
        for (int k = 0; k < 128; ++k) acc += src[k] * ldF(W, n * ld + koff + k, bf);
        if (bias) acc += ldF(bias, n, bf);
    }
    outp[oidx] = acc;
}

// ---------------------------------------------------------------------------
// K2: fused 500-step scan. 16 WGs x 256 threads (proven 216-VGPR, NO spill).
// Wave wv owns cols [32wv,32wv+32). Weights register-resident. The two
// in-loop phase syncs use LDS spin-flags (wgsync) instead of __syncthreads:
// no s_barrier => no vmcnt(0) drain => global prefetch stays in flight.
// ---------------------------------------------------------------------------
template <bool BF>
__global__ __launch_bounds__(256, 1) void dimkt_scan(
    const void* __restrict__ q_emb,
    const int* __restrict__ cI, const int* __restrict__ sI,
    const int* __restrict__ qI, const int* __restrict__ aI,
    const void* __restrict__ W1, const void* __restrict__ b1,
    const void* __restrict__ W2, const void* __restrict__ b2,
    const void* __restrict__ W3, const void* __restrict__ b3,
    const void* __restrict__ W4, const void* __restrict__ W5,
    const void* __restrict__ W6, const void* __restrict__ knowledge,
    const float* __restrict__ cW1p, const float* __restrict__ sdQ,
    const float* __restrict__ qdQ, const float* __restrict__ aW6p,
    const float* __restrict__ c4t, const float* __restrict__ c5t,
    void* __restrict__ outv) {
    if (detect_bf16(q_emb) != BF) return;   // wrong specialization: uniform exit
    // 136-ushort row stride: 272B = 17*16B -> 16B-aligned ds_read_b128
    __shared__ __align__(16) u16 kbuf[16][136];
    __shared__ __align__(16) u16 qqbuf[16][136];
    __shared__ __align__(16) u16 sdbuf[16][136];
    __shared__ int sctr;

    const int tid = threadIdx.x;
    const int wv = tid >> 6, lane = tid & 63;
    const int quad = lane >> 4, l15 = lane & 15;
    const int b0 = blockIdx.x * 16;

    // ---- stationary weight fragments (registers, 500-step resident) ----
    bf16x8 fW1[2][4], fW2[2][4], fW3[2][4], fW4[2][4], fW5[2][4], fW6[2][4];
    float b1v[2], b2v[2], b3v[2], c4_0[2], c4_1[2], c5_0[2], c5_1[2];
    int col_[2];
#pragma unroll
    for (int j = 0; j < 2; ++j) {
        const int col = wv * 32 + j * 16 + l15;
        col_[j] = col;
#pragma unroll
        for (int ks = 0; ks < 4; ++ks) {
            const int ko = ks * 32 + quad * 8;
            fW1[j][ks] = ldfragT<BF>(W1, col * 512 + ko);   // W1[:, :128]
            fW2[j][ks] = ldfragT<BF>(W2, col * 128 + ko);
            fW3[j][ks] = ldfragT<BF>(W3, col * 128 + ko);
            fW4[j][ks] = ldfragT<BF>(W4, col * 256 + ko);   // W4[:, :128]
            fW5[j][ks] = ldfragT<BF>(W5, col * 256 + ko);   // W5[:, :128]
            fW6[j][ks] = ldfragT<BF>(W6, col * 512 + ko);   // W6[:, :128]
        }
        b1v[j] = ldF(b1, col, BF);
        b2v[j] = ldF(b2, col, BF);
        b3v[j] = ldF(b3, col, BF);
        c4_0[j] = c4t[col]; c4_1[j] = c4t[128 + col];
        c5_0[j] = c5t[col]; c5_1[j] = c5t[128 + col];
    }

    // ---- t=0 init: gathers, inp_0 via MFMA, kbuf/qqbuf, z6c ----
    float kold[2][4], z6c[2][4], g[2][4];
    int ac[4];
    {
        float inpAdd0[2][4];
#pragma unroll
        for (int i = 0; i < 4; ++i) {
            const int off = (b0 + quad * 4 + i) * S_LEN + 0;
            const int cx = iclamp(cI[off], 1000);
            const int sx = iclamp(sI[off], 101);
            const int qx = iclamp(qI[off], 101);
            const int ax = iclamp(aI[off], 1);
            ac[i] = ax;
            const float2 cg = *(const float2*)(cW1p + cx * 128 + wv * 32 + l15 * 2);
            const float4 sg = *(const float4*)(sdQ + sx * 256 + wv * 64 + l15 * 4);
            const float4 qg = *(const float4*)(qdQ + qx * 256 + wv * 64 + l15 * 4);
            const float2 ag = *(const float2*)(aW6p + ax * 128 + wv * 32 + l15 * 2);
            inpAdd0[0][i] = cg.x + sg.x + qg.x + b1v[0];
            inpAdd0[1][i] = cg.y + sg.y + qg.y + b1v[1];
            z6c[0][i] = ag.x + sg.z + qg.z;
            z6c[1][i] = ag.y + sg.w + qg.w;
        }
        bf16x8 ae0[4];
#pragma unroll
        for (int ks = 0; ks < 4; ++ks)
            ae0[ks] = ldfragT<BF>(q_emb, ((b0 + l15) * S_LEN + 0) * EDIM + ks * 32 + quad * 8);
        f32x4 Y1[2];
#pragma unroll
        for (int j = 0; j < 2; ++j) {
            Y1[j] = (f32x4){inpAdd0[j][0], inpAdd0[j][1], inpAdd0[j][2], inpAdd0[j][3]};
#pragma unroll
            for (int ks = 0; ks < 4; ++ks)
                Y1[j] = __builtin_amdgcn_mfma_f32_16x16x32_bf16(ae0[ks], fW1[j][ks], Y1[j], 0, 0, 0);
        }
#pragma unroll
        for (int j = 0; j < 2; ++j) {
            const float k0 = ldF(knowledge, col_[j], BF);
#pragma unroll
            for (int i = 0; i < 4; ++i) {
                kold[j][i] = k0;
                const int row = quad * 4 + i;
                kbuf[row][col_[j]] = f2bf(k0);
                qqbuf[row][col_[j]] = f2bf(k0 - Y1[j][i]);
            }
        }
    }
    // ---- prime pipeline: q_emb[1] fragments + raw idx[1] ----
    bf16x8 aeNow[4], aeFut[4];
#pragma unroll
    for (int ks = 0; ks < 4; ++ks)
        aeNow[ks] = ldfragT<BF>(q_emb, ((b0 + l15) * S_LEN + 1) * EDIM + ks * 32 + quad * 8);
    int cN[4], sN[4], qN[4], aN[4], cF[4], sF[4], qF[4], aF[4];
#pragma unroll
    for (int i = 0; i < 4; ++i) {
        const int off = (b0 + quad * 4 + i) * S_LEN + 1;
        cN[i] = cI[off]; sN[i] = sI[off]; qN[i] = qI[off]; aN[i] = aI[off];
    }
    if (tid == 0) sctr = 0;
    __syncthreads();   // one real barrier pre-loop (drains weight loads once)

    int bar = 0;
#pragma unroll 1
    for (int t = 0; t < S_LEN; ++t) {
        // ---- issue prefetch: q_emb/idx for t+2 (raw, consumed next iter) ----
        const int tf = (t + 2 < S_LEN) ? t + 2 : S_LEN - 1;
#pragma unroll
        for (int ks = 0; ks < 4; ++ks)
            aeFut[ks] = ldfragT<BF>(q_emb, ((b0 + l15) * S_LEN + tf) * EDIM + ks * 32 + quad * 8);
#pragma unroll
        for (int i = 0; i < 4; ++i) {
            const int off = (b0 + quad * 4 + i) * S_LEN + tf;
            cF[i] = cI[off]; sF[i] = sI[off]; qF[i] = qI[off]; aF[i] = aI[off];
        }
        // ---- gathers for t+1 (clamp raw idx loaded last iter; consumed late in C)
        float2 cg[4], ag[4];
        float4 sg[4], qg[4];
        int an[4];
#pragma unroll
        for (int i = 0; i < 4; ++i) {
            const int cx = iclamp(cN[i], 1000), sx = iclamp(sN[i], 101);
            const int qx = iclamp(qN[i], 101),  ax = iclamp(aN[i], 1);
            an[i] = ax;
            cg[i] = *(const float2*)(cW1p + cx * 128 + wv * 32 + l15 * 2);
            sg[i] = *(const float4*)(sdQ + sx * 256 + wv * 64 + l15 * 4);
            qg[i] = *(const float4*)(qdQ + qx * 256 + wv * 64 + l15 * 4);
            ag[i] = *(const float2*)(aW6p + ax * 128 + wv * 32 + l15 * 2);
        }

        // ---- phase B: Y2/Y3 on qq, Y6 on k, Y1n on ae(t+1); sdft -> LDS ----
        bf16x8 aq[4], ak[4];
#pragma unroll
        for (int ks = 0; ks < 4; ++ks) {
            aq[ks] = *(const bf16x8*)&qqbuf[l15][ks * 32 + quad * 8];
            ak[ks] = *(const bf16x8*)&kbuf[l15][ks * 32 + quad * 8];
        }
        f32x4 Y2[2], Y3[2], Y6[2], Y1n[2];
#pragma unroll
        for (int j = 0; j < 2; ++j) {
            Y2[j] = (f32x4){b2v[j], b2v[j], b2v[j], b2v[j]};
            Y3[j] = (f32x4){b3v[j], b3v[j], b3v[j], b3v[j]};
            Y6[j] = (f32x4){z6c[j][0], z6c[j][1], z6c[j][2], z6c[j][3]};
            Y1n[j] = (f32x4){b1v[j], b1v[j], b1v[j], b1v[j]};
#pragma unroll
            for (int ks = 0; ks < 4; ++ks) {
                Y2[j] = __builtin_amdgcn_mfma_f32_16x16x32_bf16(aq[ks], fW2[j][ks], Y2[j], 0, 0, 0);
                Y3[j] = __builtin_amdgcn_mfma_f32_16x16x32_bf16(aq[ks], fW3[j][ks], Y3[j], 0, 0, 0);
                Y6[j] = __builtin_amdgcn_mfma_f32_16x16x32_bf16(ak[ks], fW6[j][ks], Y6[j], 0, 0, 0);
                Y1n[j] = __builtin_amdgcn_mfma_f32_16x16x32_bf16(aeNow[ks], fW1[j][ks], Y1n[j], 0, 0, 0);
            }
        }
#pragma unroll
        for (int j = 0; j < 2; ++j)
#pragma unroll
            for (int i = 0; i < 4; ++i) {
                const float sdv = sigm(Y2[j][i]) * tanh_(Y3[j][i]);
                sdbuf[quad * 4 + i][col_[j]] = f2bf(sdv);
                g[j][i] = sigm(Y6[j][i]);
            }
        bar += 4; wgsync(&sctr, bar);

        // ---- phase C: Y4/Y5 on sdft; k update; write k/qq for t+1 ----
        bf16x8 as[4];
#pragma unroll
        for (int ks = 0; ks < 4; ++ks)
            as[ks] = *(const bf16x8*)&sdbuf[l15][ks * 32 + quad * 8];
        f32x4 Y4[2], Y5[2];
#pragma unroll
        for (int j = 0; j < 2; ++j) {
            Y4[j] = (f32x4){ac[0] ? c4_1[j] : c4_0[j], ac[1] ? c4_1[j] : c4_0[j],
                            ac[2] ? c4_1[j] : c4_0[j], ac[3] ? c4_1[j] : c4_0[j]};
            Y5[j] = (f32x4){ac[0] ? c5_1[j] : c5_0[j], ac[1] ? c5_1[j] : c5_0[j],
                            ac[2] ? c5_1[j] : c5_0[j], ac[3] ? c5_1[j] : c5_0[j]};
#pragma unroll
            for (int ks = 0; ks < 4; ++ks) {
                Y4[j] = __builtin_amdgcn_mfma_f32_16x16x32_bf16(as[ks], fW4[j][ks], Y4[j], 0, 0, 0);
                Y5[j] = __builtin_amdgcn_mfma_f32_16x16x32_bf16(as[ks], fW5[j][ks], Y5[j], 0, 0, 0);
            }
        }
#pragma unroll
        for (int j = 0; j < 2; ++j)
#pragma unroll
            for (int i = 0; i < 4; ++i) {
                const float pk = sigm(Y4[j][i]) * tanh_(Y5[j][i]);
                const float kn = g[j][i] * kold[j][i] + (1.0f - g[j][i]) * pk;
                kold[j][i] = kn;
                const float inpn = Y1n[j][i] +
                    ((j == 0) ? (cg[i].x + sg[i].x + qg[i].x) : (cg[i].y + sg[i].y + qg[i].y));
                const int row = quad * 4 + i;
                kbuf[row][col_[j]] = f2bf(kn);
                qqbuf[row][col_[j]] = f2bf(kn - inpn);   // qq_{t+1}
            }
        // ---- rotate pipeline registers; z6 for t+1 ----
#pragma unroll
        for (int i = 0; i < 4; ++i) {
            z6c[0][i] = ag[i].x + sg[i].z + qg[i].z;
            z6c[1][i] = ag[i].y + sg[i].w + qg[i].w;
            ac[i] = an[i];
            cN[i] = cF[i]; sN[i] = sF[i]; qN[i] = qF[i]; aN[i] = aF[i];
        }
#pragma unroll
        for (int ks = 0; ks < 4; ++ks) aeNow[ks] = aeFut[ks];
        bar += 4; wgsync(&sctr, bar);
    }

    // ---- epilogue: out = sigmoid(k_final), [B][E], dtype matches input ----
#pragma unroll
    for (int j = 0; j < 2; ++j)
#pragma unroll
        for (int i = 0; i < 4; ++i) {
            const int row = quad * 4 + i;
            const float v = sigm(kold[j][i]);
            const int off = (b0 + row) * EDIM + col_[j];
            if (BF) ((u16*)outv)[off] = f2bf(v);
            else    ((float*)outv)[off] = v;
        }
}

// ---------------------------------------------------------------------------
extern "C" void kernel_launch(void* const* d_in, const int* in_sizes, int n_in,
                              void* d_out, int out_size, void* d_ws, size_t ws_size,
                              hipStream_t stream) {
    static const int exp_sizes[27] = {
        128000, 128000, 128000, 128000, 128000,
        128000, 128000, 128000, 128000,
        16384000,
        128128, 13056, 13056, 256, 128,
        65536, 128, 16384, 128, 16384, 128,
        32768, 128, 32768, 128, 65536, 128
    };
    bool sizes_ok = (n_in == 27) && (out_size == 32768);
    if (sizes_ok)
        for (int i = 0; i < 27; ++i)
            if (in_sizes[i] != exp_sizes[i]) { sizes_ok = false; break; }
    if (!sizes_ok) {
        dimkt_sentinel<<<dim3(128), dim3(256), 0, stream>>>((u16*)d_out, (u16)0xC080); // -4.0
        return;
    }
    const size_t WS_NEED = 724480;
    if (ws_size < WS_NEED) {
        dimkt_sentinel<<<dim3(128), dim3(256), 0, stream>>>((u16*)d_out, (u16)0x4110); // 9.0
        return;
    }

    const int* c   = (const int*)d_in[1];
    const int* sd  = (const int*)d_in[2];
    const int* qd  = (const int*)d_in[3];
    const int* a   = (const int*)d_in[4];
    const void* q_emb = d_in[9];
    const void* c_tab = d_in[10];
    const void* sd_tab = d_in[11];
    const void* qd_tab = d_in[12];
    const void* a_tab = d_in[13];
    const void* knowledge = d_in[14];
    const void* W1 = d_in[15]; const void* b1 = d_in[16];
    const void* W2 = d_in[17]; const void* b2 = d_in[18];
    const void* W3 = d_in[19]; const void* b3 = d_in[20];
    const void* W4 = d_in[21]; const void* b4 = d_in[22];
    const void* W5 = d_in[23]; const void* b5 = d_in[24];
    const void* W6 = d_in[25]; const void* b6 = d_in[26];

    float* wsf = (float*)d_ws;
    float* cW1p = wsf;                 // 1001*128
    float* sdQ  = wsf + 128128;        // 102*256
    float* qdQ  = wsf + 154240;        // 102*256
    float* aW6p = wsf + 180352;        // 2*128 (+b6)
    float* c4t  = wsf + 180608;        // 2*128 (+b4)
    float* c5t  = wsf + 180864;        // 2*128 (+b5), ends at 181120 floats

    dimkt_tabs<<<dim3(1415), dim3(128), 0, stream>>>(
        q_emb, c_tab, sd_tab, qd_tab, a_tab, W1, W4, W5, W6, b4, b5, b6,
        cW1p, sdQ, qdQ, aW6p, c4t, c5t);

    dimkt_scan<true><<<dim3(16), dim3(256), 0, stream>>>(
        q_emb, c, sd, qd, a, W1, b1, W2, b2, W3, b3, W4, W5, W6, knowledge,
        cW1p, sdQ, qdQ, aW6p, c4t, c5t, d_out);
    dimkt_scan<false><<<dim3(16), dim3(256), 0, stream>>>(
        q_emb, c, sd, qd, a, W1, b1, W2, b2, W3, b3, W4, W5, W6, knowledge,
        cW1p, sdQ, qdQ, aW6p, c4t, c5t, d_out);
}